// Round 1
// baseline (797.931 us; speedup 1.0000x reference)
//
#include <hip/hip_runtime.h>

#define M_ROWS 16384
#define N_CODES 8192
#define K_DIM   256

#define BM 128
#define BN 128
#define BK 16
#define NSPLIT 8
#define NCPB (N_CODES / NSPLIT)   // 1024 cols per block
#define NCHUNKS (NCPB / BN)       // 8
#define KCHUNKS (K_DIM / BK)      // 16

// ---------------- transpose: out[c][r] = in[r][c] ----------------
__global__ void transpose_k(const float* __restrict__ in, float* __restrict__ out,
                            int R, int C) {
  __shared__ float tile[32][33];
  const int c0 = blockIdx.x * 32;
  const int r0 = blockIdx.y * 32;
  const int tx = threadIdx.x;   // 0..31
  const int ty = threadIdx.y;   // 0..7
#pragma unroll
  for (int j = 0; j < 32; j += 8)
    tile[ty + j][tx] = in[(size_t)(r0 + ty + j) * C + c0 + tx];
  __syncthreads();
#pragma unroll
  for (int j = 0; j < 32; j += 8)
    out[(size_t)(c0 + ty + j) * R + r0 + tx] = tile[tx][ty + j];
}

// ---------------- ||e||^2 per codebook row (1 wave per row) ----------------
__global__ void enorm_k(const float* __restrict__ cb, float* __restrict__ en) {
  const int row = blockIdx.x * 4 + (threadIdx.x >> 6);
  const int lane = threadIdx.x & 63;
  const float4 v = *reinterpret_cast<const float4*>(cb + (size_t)row * K_DIM + lane * 4);
  float s = v.x * v.x + v.y * v.y + v.z * v.z + v.w * v.w;
#pragma unroll
  for (int o = 32; o > 0; o >>= 1) s += __shfl_down(s, o, 64);
  if (lane == 0) en[row] = s;
}

// ---------------- fused distance + per-block argmin ----------------
// score = 2*x.e - ||e||^2 ; argmin d == argmax score (||x||^2 is per-row const)
#define STAGE(buf, kkv)                                                         \
  {                                                                             \
    _Pragma("unroll")                                                           \
    for (int qq = 0; qq < 2; ++qq) {                                            \
      const int q = wave + qq * 4;                                              \
      const int f = q * 256 + lane * 4;                                         \
      const int kp = f >> 7, c = f & 127;                                       \
      const float* ga = AT + (size_t)((kkv) * BK + kp) * M_ROWS + m_base + c;   \
      __builtin_amdgcn_global_load_lds(                                         \
          (const __attribute__((address_space(1))) void*)ga,                    \
          (__attribute__((address_space(3))) void*)(&As[buf][0][0] + q * 256),  \
          16, 0, 0);                                                            \
      const float* gb = BT + (size_t)((kkv) * BK + kp) * N_CODES + n_base + c;  \
      __builtin_amdgcn_global_load_lds(                                         \
          (const __attribute__((address_space(1))) void*)gb,                    \
          (__attribute__((address_space(3))) void*)(&Bs[buf][0][0] + q * 256),  \
          16, 0, 0);                                                            \
    }                                                                           \
  }

__global__ __launch_bounds__(256, 2)
void vq_dist(const float* __restrict__ AT, const float* __restrict__ BT,
             const float* __restrict__ en, float* __restrict__ candV,
             int* __restrict__ candI) {
  __shared__ float As[2][BK][BM];
  __shared__ float Bs[2][BK][BN];
  const int tid = threadIdx.x;
  const int ty = tid >> 4, tx = tid & 15;
  const int wave = tid >> 6, lane = tid & 63;
  const int m_base = blockIdx.x * BM;
  const int nsplit = blockIdx.y;

  float best[8];
  int bidx[8];
#pragma unroll
  for (int i = 0; i < 8; ++i) { best[i] = -3.0e38f; bidx[i] = 0; }

  for (int nc = 0; nc < NCHUNKS; ++nc) {
    const int n_base = nsplit * NCPB + nc * BN;
    float acc[8][8];
#pragma unroll
    for (int i = 0; i < 8; ++i)
#pragma unroll
      for (int j = 0; j < 8; ++j) acc[i][j] = 0.f;

    STAGE(0, 0);
    __syncthreads();

    for (int kk = 0; kk < KCHUNKS; ++kk) {
      const int cur = kk & 1;
      if (kk + 1 < KCHUNKS) STAGE(cur ^ 1, kk + 1);
#pragma unroll
      for (int kp = 0; kp < BK; ++kp) {
        const float4 a0 = *reinterpret_cast<const float4*>(&As[cur][kp][ty * 8]);
        const float4 a1 = *reinterpret_cast<const float4*>(&As[cur][kp][ty * 8 + 4]);
        const float4 b0 = *reinterpret_cast<const float4*>(&Bs[cur][kp][tx * 4]);
        const float4 b1 = *reinterpret_cast<const float4*>(&Bs[cur][kp][64 + tx * 4]);
        const float av[8] = {a0.x, a0.y, a0.z, a0.w, a1.x, a1.y, a1.z, a1.w};
        const float bv[8] = {b0.x, b0.y, b0.z, b0.w, b1.x, b1.y, b1.z, b1.w};
#pragma unroll
        for (int i = 0; i < 8; ++i)
#pragma unroll
          for (int j = 0; j < 8; ++j) acc[i][j] = fmaf(av[i], bv[j], acc[i][j]);
      }
      __syncthreads();
    }

    const float4 e0 = *reinterpret_cast<const float4*>(&en[n_base + tx * 4]);
    const float4 e1 = *reinterpret_cast<const float4*>(&en[n_base + 64 + tx * 4]);
    const float ev[8] = {e0.x, e0.y, e0.z, e0.w, e1.x, e1.y, e1.z, e1.w};
#pragma unroll
    for (int j = 0; j < 8; ++j) {
      const int n = n_base + ((j < 4) ? (tx * 4 + j) : (64 + tx * 4 + (j - 4)));
#pragma unroll
      for (int i = 0; i < 8; ++i) {
        const float s = 2.0f * acc[i][j] - ev[j];
        if (s > best[i]) { best[i] = s; bidx[i] = n; }
      }
    }
  }

  // cross-tx reduce per row (16 candidates per row), via LDS scratch reuse
  float* sv = &As[0][0][0];               // 128*16 floats = 8KB (fits)
  int* si = (int*)&Bs[0][0][0];           // 128*16 ints
#pragma unroll
  for (int i = 0; i < 8; ++i) {
    sv[(ty * 8 + i) * 16 + tx] = best[i];
    si[(ty * 8 + i) * 16 + tx] = bidx[i];
  }
  __syncthreads();
  if (tid < 128) {
    float bv = sv[tid * 16];
    int bi = si[tid * 16];
#pragma unroll
    for (int t = 1; t < 16; ++t) {
      const float v = sv[tid * 16 + t];
      const int ii = si[tid * 16 + t];
      if (v > bv || (v == bv && ii < bi)) { bv = v; bi = ii; }
    }
    candV[(size_t)(m_base + tid) * NSPLIT + nsplit] = bv;
    candI[(size_t)(m_base + tid) * NSPLIT + nsplit] = bi;
  }
}

// ---------------- reduce N-split candidates to final index ----------------
__global__ void vq_reduce(const float* __restrict__ candV, const int* __restrict__ candI,
                          float* __restrict__ idxf, int* __restrict__ ind) {
  const int row = blockIdx.x * blockDim.x + threadIdx.x;
  if (row >= M_ROWS) return;
  float bv = candV[(size_t)row * NSPLIT];
  int bi = candI[(size_t)row * NSPLIT];
#pragma unroll
  for (int s = 1; s < NSPLIT; ++s) {
    const float v = candV[(size_t)row * NSPLIT + s];
    const int ii = candI[(size_t)row * NSPLIT + s];
    if (v > bv || (v == bv && ii < bi)) { bv = v; bi = ii; }
  }
  ind[row] = bi;
  idxf[row] = (float)bi;   // indices written as float32 into concatenated out buf
}

// ---------------- gather z_q, write z_q_st, partial loss sums ----------------
__global__ void vq_gather(const float* __restrict__ x, const float* __restrict__ cb,
                          const int* __restrict__ ind, float* __restrict__ zq,
                          float* __restrict__ partial) {
  __shared__ float red[256];
  const int g = blockIdx.x * 256 + threadIdx.x;  // float4 index
  const int row = g >> 6;
  const int c4 = g & 63;
  const int idx = ind[row];
  const float4 z = *reinterpret_cast<const float4*>(cb + (size_t)idx * K_DIM + c4 * 4);
  const float4 xv = *reinterpret_cast<const float4*>(x + (size_t)g * 4);
  *reinterpret_cast<float4*>(zq + (size_t)g * 4) = z;  // z_q_st value == z_q
  const float dx = z.x - xv.x, dy = z.y - xv.y, dz = z.z - xv.z, dw = z.w - xv.w;
  red[threadIdx.x] = dx * dx + dy * dy + dz * dz + dw * dw;
  __syncthreads();
  for (int o = 128; o > 0; o >>= 1) {
    if (threadIdx.x < o) red[threadIdx.x] += red[threadIdx.x + o];
    __syncthreads();
  }
  if (threadIdx.x == 0) partial[blockIdx.x] = red[0];
}

__global__ void vq_loss(const float* __restrict__ partial, float* __restrict__ out) {
  __shared__ float red[256];
  float s = 0.f;
  for (int i = threadIdx.x; i < 4096; i += 256) s += partial[i];
  red[threadIdx.x] = s;
  __syncthreads();
  for (int o = 128; o > 0; o >>= 1) {
    if (threadIdx.x < o) red[threadIdx.x] += red[threadIdx.x + o];
    __syncthreads();
  }
  if (threadIdx.x == 0) out[0] = 1.25f * red[0] / 4194304.0f;
}

extern "C" void kernel_launch(void* const* d_in, const int* in_sizes, int n_in,
                              void* d_out, int out_size, void* d_ws, size_t ws_size,
                              hipStream_t stream) {
  const float* x = (const float*)d_in[0];
  const float* cb = (const float*)d_in[1];
  float* out = (float*)d_out;
  float* zq = out;                   // [0, 4194304)
  float* loss = out + 4194304;       // [4194304]
  float* idxf = out + 4194305;       // [4194305, 4210689)

  float* AT = (float*)d_ws;                            // 16384*256
  float* BT = AT + (size_t)M_ROWS * K_DIM;             // 8192*256
  float* en = BT + (size_t)N_CODES * K_DIM;            // 8192
  float* cV = en + N_CODES;                            // 16384*8
  int* cI = (int*)(cV + (size_t)M_ROWS * NSPLIT);      // 16384*8
  int* ind = cI + (size_t)M_ROWS * NSPLIT;             // 16384
  float* part = (float*)(ind + M_ROWS);                // 4096

  transpose_k<<<dim3(K_DIM / 32, M_ROWS / 32), dim3(32, 8), 0, stream>>>(x, AT, M_ROWS, K_DIM);
  transpose_k<<<dim3(K_DIM / 32, N_CODES / 32), dim3(32, 8), 0, stream>>>(cb, BT, N_CODES, K_DIM);
  enorm_k<<<N_CODES / 4, 256, 0, stream>>>(cb, en);
  vq_dist<<<dim3(M_ROWS / BM, NSPLIT), 256, 0, stream>>>(AT, BT, en, cV, cI);
  vq_reduce<<<M_ROWS / 256, 256, 0, stream>>>(cV, cI, idxf, ind);
  vq_gather<<<4194304 / (256 * 4), 256, 0, stream>>>(x, cb, ind, zq, part);
  vq_loss<<<1, 256, 0, stream>>>(part, loss);
}

// Round 2
// 400.036 us; speedup vs baseline: 1.9946x; 1.9946x over previous
//
#include <hip/hip_runtime.h>

#define M_ROWS 16384
#define N_CODES 8192
#define K_DIM   256
#define NSPLIT  8
#define NCPB    1024      // codes per block (column of splits)
#define CAP     4096      // risky-row capacity
#define TAU     0.02f     // margin threshold in acc units (d-margin = 2*TAU)

typedef _Float16 half8 __attribute__((ext_vector_type(8)));
typedef float floatx16 __attribute__((ext_vector_type(16)));

#define GLL16(g, l) __builtin_amdgcn_global_load_lds(                         \
    (const __attribute__((address_space(1))) void*)(g),                       \
    (__attribute__((address_space(3))) void*)(l), 16, 0, 0)
#define GLL4(g, l) __builtin_amdgcn_global_load_lds(                          \
    (const __attribute__((address_space(1))) void*)(g),                       \
    (__attribute__((address_space(3))) void*)(l), 4, 0, 0)

// ---- zero the risky counter (graph-safe, re-run every launch) ----
__global__ void zero_k(int* cnt) { if (threadIdx.x == 0) *cnt = 0; }

// ---- split fp32 rows into swizzled fp16 h/l tile blobs ----
// blob layout per (tile of 128 rows, kchunk of 64): 32KB = h-image 16KB || l-image 16KB
// h-image byte: r*128 + ((g ^ (r&7))<<4) + j*2   (g = k-granule 0..7, j = 0..7)
__global__ void pack_k(const float* __restrict__ in, _Float16* __restrict__ out) {
  const int t = blockIdx.x * 256 + threadIdx.x;
  const int R = t >> 5;            // source row
  const int G = t & 31;            // granule over full K (256/8)
  const int c = G >> 3, g = G & 7;
  const int r = R & 127, tile = R >> 7;
  const float* src = in + (size_t)R * K_DIM + G * 8;
  half8 hv, lv;
#pragma unroll
  for (int j = 0; j < 8; ++j) {
    const float v = src[j];
    const _Float16 h = (_Float16)v;
    hv[j] = h;
    lv[j] = (_Float16)(v - (float)h);
  }
  _Float16* blob = out + (size_t)(tile * 4 + c) * 16384;
  const int off = r * 64 + ((g ^ (r & 7)) * 8);
  *reinterpret_cast<half8*>(blob + off) = hv;
  *reinterpret_cast<half8*>(blob + 8192 + off) = lv;
}

// ---- en2[c] = 0.5*||e_c||^2 (exact fp32) ----
__global__ void enorm_k(const float* __restrict__ cb, float* __restrict__ en2) {
  const int row = blockIdx.x * 4 + (threadIdx.x >> 6);
  const int lane = threadIdx.x & 63;
  const float4 v = *reinterpret_cast<const float4*>(cb + (size_t)row * K_DIM + lane * 4);
  float s = v.x * v.x + v.y * v.y + v.z * v.z + v.w * v.w;
#pragma unroll
  for (int o = 32; o > 0; o >>= 1) s += __shfl_down(s, o, 64);
  if (lane == 0) en2[row] = 0.5f * s;
}

// ---- fused split-f16 MFMA distance + per-(row,split) top-2 ----
// A-operand = codebook tile (rows=codes), B-operand = x tile (cols=x-rows)
// acc[i][j] = sum_k e[code][k]*x[row][k]; score = acc - en2[code]
__global__ __launch_bounds__(256, 2)
void vq_dist(const _Float16* __restrict__ Apack, const _Float16* __restrict__ Bpack,
             const float* __restrict__ en2, float* __restrict__ candV,
             int* __restrict__ candI, float* __restrict__ cand2) {
  __shared__ _Float16 ldsA[16384];   // Ah[8192] || Al[8192]  (32KB)
  __shared__ _Float16 ldsB[16384];   // Bh || Bl              (32KB)
  __shared__ float ldsE[128];
  __shared__ float scr[2][128][3];

  const int tid = threadIdx.x;
  const int wv = tid >> 6, lane = tid & 63;
  const int wA = wv & 1, wB = wv >> 1;     // code-half, xrow-half
  const int l31 = lane & 31, lh = lane >> 5;
  const int bx = blockIdx.x, ns = blockIdx.y;

  const int rA = wA * 64 + l31;   // code row within 128 (+i*32)
  const int rB = wB * 64 + l31;   // x row within 128 (+j*32)

  float b1[2] = {-3.0e38f, -3.0e38f};
  float b2[2] = {-3.0e38f, -3.0e38f};
  int i1[2] = {0, 0};

  for (int nc = 0; nc < 8; ++nc) {
    const int nbase = ns * NCPB + nc * 128;
    floatx16 acc[2][2] = {};

    for (int st = 0; st < 4; ++st) {
      __syncthreads();   // previous compute done before LDS overwrite
      const _Float16* ga = Apack + (size_t)((nbase >> 7) * 4 + st) * 16384;
      const _Float16* gb = Bpack + (size_t)(bx * 4 + st) * 16384;
#pragma unroll
      for (int q = 0; q < 8; ++q) {
        const int sec = (wv * 8 + q) * 512;          // fp16 units (1KB per wave-instr)
        GLL16(ga + sec + lane * 8, ldsA + sec);
        GLL16(gb + sec + lane * 8, ldsB + sec);
      }
      if (st == 0 && wv < 2) GLL4(en2 + nbase + wv * 64 + lane, ldsE + wv * 64);
      __syncthreads();   // vmcnt(0)+lgkmcnt(0) drained by compiler before barrier

#pragma unroll
      for (int ks = 0; ks < 4; ++ks) {
        const int g = ks * 2 + lh;                   // k-granule 0..7
        half8 ah[2], al[2], bh[2], bl[2];
#pragma unroll
        for (int i = 0; i < 2; ++i) {
          const int ra = rA + i * 32;
          const int offA = ra * 64 + ((g ^ (ra & 7)) * 8);
          ah[i] = *reinterpret_cast<const half8*>(ldsA + offA);
          al[i] = *reinterpret_cast<const half8*>(ldsA + 8192 + offA);
          const int rb = rB + i * 32;
          const int offB = rb * 64 + ((g ^ (rb & 7)) * 8);
          bh[i] = *reinterpret_cast<const half8*>(ldsB + offB);
          bl[i] = *reinterpret_cast<const half8*>(ldsB + 8192 + offB);
        }
#pragma unroll
        for (int i = 0; i < 2; ++i)
#pragma unroll
          for (int j = 0; j < 2; ++j) {
            acc[i][j] = __builtin_amdgcn_mfma_f32_32x32x16_f16(ah[i], bh[j], acc[i][j], 0, 0, 0);
            acc[i][j] = __builtin_amdgcn_mfma_f32_32x32x16_f16(ah[i], bl[j], acc[i][j], 0, 0, 0);
            acc[i][j] = __builtin_amdgcn_mfma_f32_32x32x16_f16(al[i], bh[j], acc[i][j], 0, 0, 0);
          }
      }
    }

    // epilogue: score + running per-lane top-2 (lane's x-rows fixed: rB + j*32)
#pragma unroll
    for (int i = 0; i < 2; ++i) {
#pragma unroll
      for (int reg = 0; reg < 16; ++reg) {
        const int crow = (reg & 3) + 8 * (reg >> 2) + 4 * lh;
        const int cloc = wA * 64 + i * 32 + crow;
        const float e = ldsE[cloc];
        const int code = nbase + cloc;
#pragma unroll
        for (int j = 0; j < 2; ++j) {
          const float v = acc[i][j][reg] - e;
          if (v > b1[j] || (v == b1[j] && code < i1[j])) {
            b2[j] = b1[j]; b1[j] = v; i1[j] = code;
          } else if (v > b2[j]) {
            b2[j] = v;
          }
        }
      }
    }
  }

  // merge lane <-> lane^32 (same x-row, disjoint code subsets)
#pragma unroll
  for (int j = 0; j < 2; ++j) {
    const float o1 = __shfl_xor(b1[j], 32, 64);
    const int oi = __shfl_xor(i1[j], 32, 64);
    const float o2 = __shfl_xor(b2[j], 32, 64);
    const bool win = (b1[j] > o1) || (b1[j] == o1 && i1[j] < oi);
    const float lose1 = win ? o1 : b1[j];
    b1[j] = win ? b1[j] : o1;
    i1[j] = win ? i1[j] : oi;
    b2[j] = fmaxf(fmaxf(b2[j], o2), lose1);
  }

  __syncthreads();
  if (lane < 32) {
#pragma unroll
    for (int j = 0; j < 2; ++j) {
      const int row = wB * 64 + j * 32 + l31;
      scr[wA][row][0] = b1[j];
      scr[wA][row][1] = __int_as_float(i1[j]);
      scr[wA][row][2] = b2[j];
    }
  }
  __syncthreads();
  if (tid < 128) {
    float v1 = scr[0][tid][0]; int ii = __float_as_int(scr[0][tid][1]); float v2 = scr[0][tid][2];
    const float o1 = scr[1][tid][0]; const int oi = __float_as_int(scr[1][tid][1]); const float o2 = scr[1][tid][2];
    const bool win = (v1 > o1) || (v1 == o1 && ii < oi);
    const float lose1 = win ? o1 : v1;
    const float nb1 = win ? v1 : o1;
    const int ni = win ? ii : oi;
    const float nb2 = fmaxf(fmaxf(v2, o2), lose1);
    const int row = bx * 128 + tid;
    candV[(size_t)row * NSPLIT + ns] = nb1;
    candI[(size_t)row * NSPLIT + ns] = ni;
    cand2[(size_t)row * NSPLIT + ns] = nb2;
  }
}

// ---- merge splits -> index, margin; flag risky rows ----
__global__ void vq_reduce(const float* __restrict__ candV, const int* __restrict__ candI,
                          const float* __restrict__ cand2, int* __restrict__ ind,
                          int* __restrict__ cnt, int* __restrict__ risky,
                          unsigned long long* __restrict__ key) {
  const int row = blockIdx.x * blockDim.x + threadIdx.x;
  if (row >= M_ROWS) return;
  float b1 = candV[(size_t)row * NSPLIT];
  int i1 = candI[(size_t)row * NSPLIT];
  float b2 = cand2[(size_t)row * NSPLIT];
#pragma unroll
  for (int s = 1; s < NSPLIT; ++s) {
    const float v = candV[(size_t)row * NSPLIT + s];
    const int ii = candI[(size_t)row * NSPLIT + s];
    const float v2 = cand2[(size_t)row * NSPLIT + s];
    if (v > b1 || (v == b1 && ii < i1)) {
      b2 = fmaxf(b1, v2); b1 = v; i1 = ii;
    } else {
      b2 = fmaxf(b2, v);
    }
  }
  ind[row] = i1;
  if (b1 - b2 < TAU) {
    const int p = atomicAdd(cnt, 1);
    if (p < CAP) { risky[p] = row; key[row] = 0ull; }
  }
}

// ---- exact fp32 rescore of risky rows (deterministic atomicMax) ----
__global__ __launch_bounds__(256)
void vq_refine(const float* __restrict__ x, const float* __restrict__ cb,
               const float* __restrict__ en2, const int* __restrict__ cnt,
               const int* __restrict__ risky, unsigned long long* __restrict__ key) {
  __shared__ float cbs[16][256];
  __shared__ float xs[256];
  const int tid = threadIdx.x;
  const int cBase = blockIdx.x * 16;
#pragma unroll
  for (int q = 0; q < 16; ++q) cbs[q][tid] = cb[(size_t)(cBase + q) * K_DIM + tid];
  const int n = min(*cnt, CAP);
  const int sub = tid & 15;   // k-slice
  const int cl = tid >> 4;    // local code
  for (int t = 0; t < n; ++t) {
    const int row = risky[t];
    __syncthreads();
    xs[tid] = x[(size_t)row * K_DIM + tid];
    __syncthreads();
    float s = 0.f;
#pragma unroll
    for (int k = 0; k < 16; ++k) s = fmaf(xs[sub * 16 + k], cbs[cl][sub * 16 + k], s);
    s += __shfl_xor(s, 1, 64); s += __shfl_xor(s, 2, 64);
    s += __shfl_xor(s, 4, 64); s += __shfl_xor(s, 8, 64);
    if (sub == 0) {
      const int code = cBase + cl;
      const float sc = s - en2[code];
      unsigned u = __float_as_uint(sc);
      u ^= (u >> 31) ? 0xFFFFFFFFu : 0x80000000u;
      const unsigned long long k64 =
          ((unsigned long long)u << 32) | (unsigned)(N_CODES - 1 - code);
      atomicMax(key + row, k64);
    }
  }
}

__global__ void vq_fix(const int* __restrict__ cnt, const int* __restrict__ risky,
                       const unsigned long long* __restrict__ key, int* __restrict__ ind) {
  const int i = blockIdx.x * blockDim.x + threadIdx.x;
  const int n = min(*cnt, CAP);
  if (i < n) {
    const int r = risky[i];
    ind[r] = N_CODES - 1 - (int)(unsigned)(key[r] & 0xFFFFFFFFull);
  }
}

// ---- gather z_q, write z_q_st + indices, partial loss sums ----
__global__ void vq_gather(const float* __restrict__ x, const float* __restrict__ cb,
                          const int* __restrict__ ind, float* __restrict__ zq,
                          float* __restrict__ idxf, float* __restrict__ partial) {
  __shared__ float red[256];
  const int g = blockIdx.x * 256 + threadIdx.x;  // float4 index
  const int row = g >> 6;
  const int c4 = g & 63;
  const int idx = ind[row];
  if (c4 == 0) idxf[row] = (float)idx;
  const float4 z = *reinterpret_cast<const float4*>(cb + (size_t)idx * K_DIM + c4 * 4);
  const float4 xv = *reinterpret_cast<const float4*>(x + (size_t)g * 4);
  *reinterpret_cast<float4*>(zq + (size_t)g * 4) = z;
  const float dx = z.x - xv.x, dy = z.y - xv.y, dz = z.z - xv.z, dw = z.w - xv.w;
  red[threadIdx.x] = dx * dx + dy * dy + dz * dz + dw * dw;
  __syncthreads();
  for (int o = 128; o > 0; o >>= 1) {
    if (threadIdx.x < o) red[threadIdx.x] += red[threadIdx.x + o];
    __syncthreads();
  }
  if (threadIdx.x == 0) partial[blockIdx.x] = red[0];
}

__global__ void vq_loss(const float* __restrict__ partial, float* __restrict__ out) {
  __shared__ float red[256];
  float s = 0.f;
  for (int i = threadIdx.x; i < 4096; i += 256) s += partial[i];
  red[threadIdx.x] = s;
  __syncthreads();
  for (int o = 128; o > 0; o >>= 1) {
    if (threadIdx.x < o) red[threadIdx.x] += red[threadIdx.x + o];
    __syncthreads();
  }
  if (threadIdx.x == 0) out[0] = 1.25f * red[0] / 4194304.0f;
}

extern "C" void kernel_launch(void* const* d_in, const int* in_sizes, int n_in,
                              void* d_out, int out_size, void* d_ws, size_t ws_size,
                              hipStream_t stream) {
  const float* x = (const float*)d_in[0];
  const float* cb = (const float*)d_in[1];
  float* out = (float*)d_out;
  float* zq = out;                  // [0, 4194304)
  float* loss = out + 4194304;      // [4194304]
  float* idxf = out + 4194305;      // [4194305, 4210689)

  char* w = (char*)d_ws;
  _Float16* Apack = (_Float16*)w;                      w += (size_t)N_CODES * K_DIM * 2 * 2;  // 8MB
  _Float16* Bpack = (_Float16*)w;                      w += (size_t)M_ROWS * K_DIM * 2 * 2;   // 16MB
  unsigned long long* key = (unsigned long long*)w;    w += (size_t)M_ROWS * 8;
  float* en2 = (float*)w;                              w += (size_t)N_CODES * 4;
  float* candV = (float*)w;                            w += (size_t)M_ROWS * NSPLIT * 4;
  float* cand2 = (float*)w;                            w += (size_t)M_ROWS * NSPLIT * 4;
  int* candI = (int*)w;                                w += (size_t)M_ROWS * NSPLIT * 4;
  int* ind = (int*)w;                                  w += (size_t)M_ROWS * 4;
  int* risky = (int*)w;                                w += (size_t)CAP * 4;
  int* cnt = (int*)w;                                  w += 64;
  float* part = (float*)w;                             w += 4096 * 4;

  zero_k<<<1, 64, 0, stream>>>(cnt);
  pack_k<<<(N_CODES * 32) / 256, 256, 0, stream>>>(cb, Apack);
  pack_k<<<(M_ROWS * 32) / 256, 256, 0, stream>>>(x, Bpack);
  enorm_k<<<N_CODES / 4, 256, 0, stream>>>(cb, en2);
  vq_dist<<<dim3(M_ROWS / 128, NSPLIT), 256, 0, stream>>>(Apack, Bpack, en2, candV, candI, cand2);
  vq_reduce<<<M_ROWS / 256, 256, 0, stream>>>(candV, candI, cand2, ind, cnt, risky, key);
  vq_refine<<<N_CODES / 16, 256, 0, stream>>>(x, cb, en2, cnt, risky, key);
  vq_fix<<<CAP / 256, 256, 0, stream>>>(cnt, risky, key, ind);
  vq_gather<<<4194304 / (256 * 4), 256, 0, stream>>>(x, cb, ind, zq, idxf, part);
  vq_loss<<<1, 256, 0, stream>>>(part, loss);
}

// Round 3
// 323.329 us; speedup vs baseline: 2.4679x; 1.2372x over previous
//
#include <hip/hip_runtime.h>

#define M_ROWS 16384
#define N_CODES 8192
#define K_DIM   256
#define NSPLIT  8
#define NCPB    1024
#define CAP     4096
#define TAU     0.01f
#define RSTRIDE 4

typedef _Float16 half8 __attribute__((ext_vector_type(8)));
typedef float floatx16 __attribute__((ext_vector_type(16)));

#define GLL16(g, l) __builtin_amdgcn_global_load_lds(                         \
    (const __attribute__((address_space(1))) void*)(g),                       \
    (__attribute__((address_space(3))) void*)(l), 16, 0, 0)
#define GLL4(g, l) __builtin_amdgcn_global_load_lds(                          \
    (const __attribute__((address_space(1))) void*)(g),                       \
    (__attribute__((address_space(3))) void*)(l), 4, 0, 0)

// ---- pack fp32 rows into fragment-ordered fp16 h/l chunk blobs ----
// blob for (row-tile of 128, k-chunk of 32): 16KB, fp16 layout
//   [it(4)][plane(2)][t(2)][lh(2)][rr(32)][j(8)]
// => every MFMA fragment read and every staging write is a contiguous,
//    wave-linear 1KB block (lane*16B): zero LDS bank conflicts by construction.
__global__ void pack_k(const float* __restrict__ in, _Float16* __restrict__ out) {
  const int t = blockIdx.x * 256 + threadIdx.x;
  const int R = t >> 5;          // source row
  const int G = t & 31;          // k-granule of 8 (0..31)
  const int kc = G >> 2;         // k-chunk of 32
  const int gi = G & 3;
  const int tt = gi >> 1, lh = gi & 1;
  const int tile = R >> 7, r = R & 127;
  const int it = r >> 5, rr = r & 31;
  const float* src = in + (size_t)R * K_DIM + G * 8;
  half8 hv, lv;
#pragma unroll
  for (int j = 0; j < 8; ++j) {
    const float v = src[j];
    const _Float16 h = (_Float16)v;
    hv[j] = h;
    lv[j] = (_Float16)(v - (float)h);
  }
  _Float16* blob = out + ((size_t)tile * 8 + kc) * 8192;
  const int offh = (((it * 2 + 0) * 2 + tt) * 2 + lh) * 256 + rr * 8;
  const int offl = (((it * 2 + 1) * 2 + tt) * 2 + lh) * 256 + rr * 8;
  *reinterpret_cast<half8*>(blob + offh) = hv;
  *reinterpret_cast<half8*>(blob + offl) = lv;
}

// ---- en2[c] = 0.5*||e_c||^2 (exact fp32); also zeroes the risky counter ----
__global__ void enorm_k(const float* __restrict__ cb, float* __restrict__ en2,
                        int* __restrict__ cnt) {
  if (blockIdx.x == 0 && threadIdx.x == 0) *cnt = 0;
  const int row = blockIdx.x * 4 + (threadIdx.x >> 6);
  const int lane = threadIdx.x & 63;
  const float4 v = *reinterpret_cast<const float4*>(cb + (size_t)row * K_DIM + lane * 4);
  float s = v.x * v.x + v.y * v.y + v.z * v.z + v.w * v.w;
#pragma unroll
  for (int o = 32; o > 0; o >>= 1) s += __shfl_down(s, o, 64);
  if (lane == 0) en2[row] = 0.5f * s;
}

// ---- fused split-f16 MFMA distance + per-(row,split) top-2 ----
// pipelined: double-buffered BK=32 chunks, counted vmcnt, raw barriers.
#define WAITV8 asm volatile("s_waitcnt vmcnt(8)" ::: "memory")
#define WAITV0 asm volatile("s_waitcnt vmcnt(0)" ::: "memory")
#define WAITL0 asm volatile("s_waitcnt lgkmcnt(0)" ::: "memory")
#define SBAR do { __builtin_amdgcn_sched_barrier(0); __builtin_amdgcn_s_barrier(); \
                  __builtin_amdgcn_sched_barrier(0); } while (0)

#define STAGE(buf, kcv)                                                     \
  {                                                                         \
    const _Float16* ga_ = gA + (size_t)(kcv) * 8192;                        \
    const _Float16* gb_ = gB + (size_t)(kcv) * 8192;                        \
    _Pragma("unroll")                                                       \
    for (int q = 0; q < 4; ++q) {                                           \
      const int sec = (wv * 4 + q) * 512;                                   \
      GLL16(ga_ + sec + lane * 8, ldsA + (buf) * 8192 + sec);               \
      GLL16(gb_ + sec + lane * 8, ldsB + (buf) * 8192 + sec);               \
    }                                                                       \
  }

#define COMPUTE(bufv)                                                       \
  {                                                                         \
    const int bo = (bufv) * 8192;                                           \
    __builtin_amdgcn_s_setprio(1);                                          \
    _Pragma("unroll")                                                       \
    for (int t = 0; t < 2; ++t) {                                           \
      half8 ah[2], al[2], bh[2], bl[2];                                     \
      _Pragma("unroll")                                                     \
      for (int u = 0; u < 2; ++u) {                                         \
        const int ita = wA * 2 + u;                                         \
        ah[u] = *(const half8*)(ldsA + bo + (ita * 4 + t) * 512 + lane * 8);      \
        al[u] = *(const half8*)(ldsA + bo + (ita * 4 + 2 + t) * 512 + lane * 8);  \
        const int itb = wB * 2 + u;                                         \
        bh[u] = *(const half8*)(ldsB + bo + (itb * 4 + t) * 512 + lane * 8);      \
        bl[u] = *(const half8*)(ldsB + bo + (itb * 4 + 2 + t) * 512 + lane * 8);  \
      }                                                                     \
      _Pragma("unroll")                                                     \
      for (int i = 0; i < 2; ++i)                                           \
        _Pragma("unroll")                                                   \
        for (int j = 0; j < 2; ++j) {                                       \
          acc[i][j] = __builtin_amdgcn_mfma_f32_32x32x16_f16(ah[i], bh[j], acc[i][j], 0, 0, 0); \
          acc[i][j] = __builtin_amdgcn_mfma_f32_32x32x16_f16(ah[i], bl[j], acc[i][j], 0, 0, 0); \
          acc[i][j] = __builtin_amdgcn_mfma_f32_32x32x16_f16(al[i], bh[j], acc[i][j], 0, 0, 0); \
        }                                                                   \
    }                                                                       \
    __builtin_amdgcn_s_setprio(0);                                          \
  }

__global__ __launch_bounds__(256, 2)
void vq_dist(const _Float16* __restrict__ Apack, const _Float16* __restrict__ Bpack,
             const float* __restrict__ en2, float* __restrict__ candV,
             int* __restrict__ candI, float* __restrict__ cand2) {
  __shared__ _Float16 ldsA[2 * 8192];   // 32KB double-buffered A chunks
  __shared__ _Float16 ldsB[2 * 8192];   // 32KB
  __shared__ float ldsE[128];
  __shared__ float scr[2][128][3];

  const int tid = threadIdx.x;
  const int wv = tid >> 6, lane = tid & 63;
  const int wA = wv & 1, wB = wv >> 1;
  const int l31 = lane & 31, lh = lane >> 5;
  const int bx = blockIdx.x, ns = blockIdx.y;

  const _Float16* gB = Bpack + (size_t)bx * 65536;

  float b1[2] = {-3.0e38f, -3.0e38f};
  float b2[2] = {-3.0e38f, -3.0e38f};
  int i1[2] = {0, 0};

  for (int nc = 0; nc < 8; ++nc) {
    const int nbase = ns * NCPB + nc * 128;
    const _Float16* gA = Apack + (size_t)(ns * 8 + nc) * 65536;
    floatx16 acc[2][2] = {};

    if (nc) { WAITL0; SBAR; }          // protect ldsE before re-stage
    if (wv < 2) GLL4(en2 + nbase + wv * 64 + lane, ldsE + wv * 64);
    STAGE(0, 0);
    for (int kc = 0; kc < 7; ++kc) {
      STAGE((kc + 1) & 1, kc + 1);
      WAITV8;
      SBAR;
      COMPUTE(kc & 1);
      SBAR;
    }
    WAITV0;
    SBAR;
    COMPUTE(1);

    // epilogue: score + running per-lane top-2 (lane's x-rows: wB*64 + j*32 + l31)
#pragma unroll
    for (int i = 0; i < 2; ++i) {
#pragma unroll
      for (int reg = 0; reg < 16; ++reg) {
        const int crow = (reg & 3) + 8 * (reg >> 2) + 4 * lh;
        const int cloc = wA * 64 + i * 32 + crow;
        const float e = ldsE[cloc];
        const int code = nbase + cloc;
#pragma unroll
        for (int j = 0; j < 2; ++j) {
          const float v = acc[i][j][reg] - e;
          if (v > b1[j] || (v == b1[j] && code < i1[j])) {
            b2[j] = b1[j]; b1[j] = v; i1[j] = code;
          } else if (v > b2[j]) {
            b2[j] = v;
          }
        }
      }
    }
  }

  // merge lane <-> lane^32 (same x-row, disjoint code subsets)
#pragma unroll
  for (int j = 0; j < 2; ++j) {
    const float o1 = __shfl_xor(b1[j], 32, 64);
    const int oi = __shfl_xor(i1[j], 32, 64);
    const float o2 = __shfl_xor(b2[j], 32, 64);
    const bool win = (b1[j] > o1) || (b1[j] == o1 && i1[j] < oi);
    const float lose1 = win ? o1 : b1[j];
    b1[j] = win ? b1[j] : o1;
    i1[j] = win ? i1[j] : oi;
    b2[j] = fmaxf(fmaxf(b2[j], o2), lose1);
  }

  __syncthreads();
  if (lane < 32) {
#pragma unroll
    for (int j = 0; j < 2; ++j) {
      const int row = wB * 64 + j * 32 + l31;
      scr[wA][row][0] = b1[j];
      scr[wA][row][1] = __int_as_float(i1[j]);
      scr[wA][row][2] = b2[j];
    }
  }
  __syncthreads();
  if (tid < 128) {
    float v1 = scr[0][tid][0]; int ii = __float_as_int(scr[0][tid][1]); float v2 = scr[0][tid][2];
    const float o1 = scr[1][tid][0]; const int oi = __float_as_int(scr[1][tid][1]); const float o2 = scr[1][tid][2];
    const bool win = (v1 > o1) || (v1 == o1 && ii < oi);
    const float lose1 = win ? o1 : v1;
    const float nb1 = win ? v1 : o1;
    const int ni = win ? ii : oi;
    const float nb2 = fmaxf(fmaxf(v2, o2), lose1);
    const int row = bx * 128 + tid;
    candV[(size_t)row * NSPLIT + ns] = nb1;
    candI[(size_t)row * NSPLIT + ns] = ni;
    cand2[(size_t)row * NSPLIT + ns] = nb2;
  }
}

// ---- merge splits -> index, margin; flag risky rows ----
__global__ void vq_reduce(const float* __restrict__ candV, const int* __restrict__ candI,
                          const float* __restrict__ cand2, int* __restrict__ ind,
                          int* __restrict__ cnt, int* __restrict__ risky,
                          unsigned long long* __restrict__ key) {
  const int row = blockIdx.x * blockDim.x + threadIdx.x;
  if (row >= M_ROWS) return;
  float b1 = candV[(size_t)row * NSPLIT];
  int i1 = candI[(size_t)row * NSPLIT];
  float b2 = cand2[(size_t)row * NSPLIT];
#pragma unroll
  for (int s = 1; s < NSPLIT; ++s) {
    const float v = candV[(size_t)row * NSPLIT + s];
    const int ii = candI[(size_t)row * NSPLIT + s];
    const float v2 = cand2[(size_t)row * NSPLIT + s];
    if (v > b1 || (v == b1 && ii < i1)) {
      b2 = fmaxf(b1, v2); b1 = v; i1 = ii;
    } else {
      b2 = fmaxf(b2, v);
    }
  }
  ind[row] = i1;
  if (b1 - b2 < TAU) {
    const int p = atomicAdd(cnt, 1);
    if (p < CAP) { risky[p] = row; key[row] = 0ull; }
  }
}

// ---- exact fp32 rescore of risky rows, striped over RSTRIDE block-columns ----
__global__ __launch_bounds__(256)
void vq_refine(const float* __restrict__ x, const float* __restrict__ cb,
               const float* __restrict__ en2, const int* __restrict__ cnt,
               const int* __restrict__ risky, unsigned long long* __restrict__ key) {
  __shared__ float cbs[16][256];
  __shared__ float xs[256];
  const int n0 = *cnt;
  const int n = n0 < CAP ? n0 : CAP;
  const int stripe = blockIdx.x;
  if (stripe >= n) return;
  const int tid = threadIdx.x;
  const int cBase = blockIdx.y * 16;
#pragma unroll
  for (int q = 0; q < 16; ++q) cbs[q][tid] = cb[(size_t)(cBase + q) * K_DIM + tid];
  const int sub = tid & 15;
  const int cl = tid >> 4;
  for (int t = stripe; t < n; t += RSTRIDE) {
    const int row = risky[t];
    __syncthreads();
    xs[tid] = x[(size_t)row * K_DIM + tid];
    __syncthreads();
    float s = 0.f;
#pragma unroll
    for (int k = 0; k < 16; ++k) s = fmaf(xs[sub * 16 + k], cbs[cl][sub * 16 + k], s);
    s += __shfl_xor(s, 1, 64); s += __shfl_xor(s, 2, 64);
    s += __shfl_xor(s, 4, 64); s += __shfl_xor(s, 8, 64);
    if (sub == 0) {
      const int code = cBase + cl;
      const float sc = s - en2[code];
      unsigned u = __float_as_uint(sc);
      u ^= (u >> 31) ? 0xFFFFFFFFu : 0x80000000u;
      const unsigned long long k64 =
          ((unsigned long long)u << 32) | (unsigned)(N_CODES - 1 - code);
      atomicMax(key + row, k64);
    }
  }
}

__global__ void vq_fix(const int* __restrict__ cnt, const int* __restrict__ risky,
                       const unsigned long long* __restrict__ key, int* __restrict__ ind) {
  const int i = blockIdx.x * blockDim.x + threadIdx.x;
  const int n = *cnt < CAP ? *cnt : CAP;
  if (i < n) {
    const int r = risky[i];
    ind[r] = N_CODES - 1 - (int)(unsigned)(key[r] & 0xFFFFFFFFull);
  }
}

// ---- gather z_q, write z_q_st + indices, partial loss sums ----
__global__ void vq_gather(const float* __restrict__ x, const float* __restrict__ cb,
                          const int* __restrict__ ind, float* __restrict__ zq,
                          float* __restrict__ idxf, float* __restrict__ partial) {
  __shared__ float red[256];
  const int g = blockIdx.x * 256 + threadIdx.x;
  const int row = g >> 6;
  const int c4 = g & 63;
  const int idx = ind[row];
  if (c4 == 0) idxf[row] = (float)idx;
  const float4 z = *reinterpret_cast<const float4*>(cb + (size_t)idx * K_DIM + c4 * 4);
  const float4 xv = *reinterpret_cast<const float4*>(x + (size_t)g * 4);
  *reinterpret_cast<float4*>(zq + (size_t)g * 4) = z;
  const float dx = z.x - xv.x, dy = z.y - xv.y, dz = z.z - xv.z, dw = z.w - xv.w;
  red[threadIdx.x] = dx * dx + dy * dy + dz * dz + dw * dw;
  __syncthreads();
  for (int o = 128; o > 0; o >>= 1) {
    if (threadIdx.x < o) red[threadIdx.x] += red[threadIdx.x + o];
    __syncthreads();
  }
  if (threadIdx.x == 0) partial[blockIdx.x] = red[0];
}

__global__ void vq_loss(const float* __restrict__ partial, float* __restrict__ out) {
  __shared__ float red[256];
  float s = 0.f;
  for (int i = threadIdx.x; i < 4096; i += 256) s += partial[i];
  red[threadIdx.x] = s;
  __syncthreads();
  for (int o = 128; o > 0; o >>= 1) {
    if (threadIdx.x < o) red[threadIdx.x] += red[threadIdx.x + o];
    __syncthreads();
  }
  if (threadIdx.x == 0) out[0] = 1.25f * red[0] / 4194304.0f;
}

extern "C" void kernel_launch(void* const* d_in, const int* in_sizes, int n_in,
                              void* d_out, int out_size, void* d_ws, size_t ws_size,
                              hipStream_t stream) {
  const float* x = (const float*)d_in[0];
  const float* cb = (const float*)d_in[1];
  float* out = (float*)d_out;
  float* zq = out;
  float* loss = out + 4194304;
  float* idxf = out + 4194305;

  char* w = (char*)d_ws;
  _Float16* Apack = (_Float16*)w;                      w += (size_t)N_CODES * K_DIM * 2 * 2;
  _Float16* Bpack = (_Float16*)w;                      w += (size_t)M_ROWS * K_DIM * 2 * 2;
  unsigned long long* key = (unsigned long long*)w;    w += (size_t)M_ROWS * 8;
  float* en2 = (float*)w;                              w += (size_t)N_CODES * 4;
  float* candV = (float*)w;                            w += (size_t)M_ROWS * NSPLIT * 4;
  float* cand2 = (float*)w;                            w += (size_t)M_ROWS * NSPLIT * 4;
  int* candI = (int*)w;                                w += (size_t)M_ROWS * NSPLIT * 4;
  int* ind = (int*)w;                                  w += (size_t)M_ROWS * 4;
  int* risky = (int*)w;                                w += (size_t)CAP * 4;
  int* cnt = (int*)w;                                  w += 64;
  float* part = (float*)w;                             w += 4096 * 4;

  pack_k<<<(N_CODES * 32) / 256, 256, 0, stream>>>(cb, Apack);
  pack_k<<<(M_ROWS * 32) / 256, 256, 0, stream>>>(x, Bpack);
  enorm_k<<<N_CODES / 4, 256, 0, stream>>>(cb, en2, cnt);
  vq_dist<<<dim3(M_ROWS / 128, NSPLIT), 256, 0, stream>>>(Apack, Bpack, en2, candV, candI, cand2);
  vq_reduce<<<M_ROWS / 256, 256, 0, stream>>>(candV, candI, cand2, ind, cnt, risky, key);
  vq_refine<<<dim3(RSTRIDE, N_CODES / 16), 256, 0, stream>>>(x, cb, en2, cnt, risky, key);
  vq_fix<<<CAP / 256, 256, 0, stream>>>(cnt, risky, key, ind);
  vq_gather<<<4194304 / (256 * 4), 256, 0, stream>>>(x, cb, ind, zq, idxf, part);
  vq_loss<<<1, 256, 0, stream>>>(part, loss);
}

// Round 4
// 319.717 us; speedup vs baseline: 2.4957x; 1.0113x over previous
//
#include <hip/hip_runtime.h>

#define M_ROWS 16384
#define N_CODES 8192
#define K_DIM   256
#define NSPLIT  4
#define CAP     4096
#define TAU     0.01f
#define RSTRIDE 4

typedef _Float16 half8 __attribute__((ext_vector_type(8)));
typedef float floatx16 __attribute__((ext_vector_type(16)));

#define GLL16(g, l) __builtin_amdgcn_global_load_lds(                         \
    (const __attribute__((address_space(1))) void*)(g),                       \
    (__attribute__((address_space(3))) void*)(l), 16, 0, 0)

#define WAITV0 asm volatile("s_waitcnt vmcnt(0)" ::: "memory")
#define LGKM0  do { asm volatile("s_waitcnt lgkmcnt(0)" ::: "memory");        \
                    __builtin_amdgcn_sched_barrier(0); } while (0)
#define SCB __builtin_amdgcn_sched_barrier(0)
#define MFMA16(a, b, c) __builtin_amdgcn_mfma_f32_32x32x16_f16(a, b, c, 0, 0, 0)

// ---- pack fp32 rows into fragment-ordered fp16 h/l blobs ----
// blob per (row-tile of 256, k-chunk of 32): 32KB fp16 layout
//   [it(8)][plane(2)][ks(2)][lh(2)][rr(32)][j(8)]
// => staging writes (global_load_lds, lane-linear 1KB) and fragment reads
//    (ds_read_b128, contiguous 512B per half-wave) are conflict-free by construction.
__global__ void pack_k(const float* __restrict__ in, _Float16* __restrict__ out) {
  const int t = blockIdx.x * 256 + threadIdx.x;
  const int R = t >> 5;          // source row
  const int G = t & 31;          // k-granule of 8
  const int kc = G >> 2;         // k-chunk of 32
  const int gi = G & 3;
  const int ks = gi >> 1, lh = gi & 1;
  const int tile = R >> 8, r = R & 255;
  const int it = r >> 5, rr = r & 31;
  const float* src = in + (size_t)R * K_DIM + G * 8;
  half8 hv, lv;
#pragma unroll
  for (int j = 0; j < 8; ++j) {
    const float v = src[j];
    const _Float16 h = (_Float16)v;
    hv[j] = h;
    lv[j] = (_Float16)(v - (float)h);
  }
  _Float16* blob = out + ((size_t)tile * 8 + kc) * 16384;
  const int offh = ((((it * 2 + 0) * 2 + ks) * 2 + lh) * 32 + rr) * 8;
  const int offl = ((((it * 2 + 1) * 2 + ks) * 2 + lh) * 32 + rr) * 8;
  *reinterpret_cast<half8*>(blob + offh) = hv;
  *reinterpret_cast<half8*>(blob + offl) = lv;
}

// ---- en2[c] = 0.5*||e_c||^2 (exact fp32); also zeroes the risky counter ----
__global__ void enorm_k(const float* __restrict__ cb, float* __restrict__ en2,
                        int* __restrict__ cnt) {
  if (blockIdx.x == 0 && threadIdx.x == 0) *cnt = 0;
  const int row = blockIdx.x * 4 + (threadIdx.x >> 6);
  const int lane = threadIdx.x & 63;
  const float4 v = *reinterpret_cast<const float4*>(cb + (size_t)row * K_DIM + lane * 4);
  float s = v.x * v.x + v.y * v.y + v.z * v.z + v.w * v.w;
#pragma unroll
  for (int o = 32; o > 0; o >>= 1) s += __shfl_down(s, o, 64);
  if (lane == 0) en2[row] = 0.5f * s;
}

// ---- fused split-f16 MFMA distance, 256x256 tile, 8-wave 4-phase schedule ----
__global__ __launch_bounds__(512, 2)
void vq_dist(const _Float16* __restrict__ Apack, const _Float16* __restrict__ Bpack,
             const float* __restrict__ en2, float* __restrict__ candV,
             int* __restrict__ candI, float* __restrict__ cand2) {
  __shared__ _Float16 ldsA[2 * 16384];   // 64KB double-buffered A (codes) chunks
  __shared__ _Float16 ldsB[2 * 16384];   // 64KB double-buffered B (x-rows) chunks

  const int tid = threadIdx.x;
  const int wv = tid >> 6, lane = tid & 63;
  const int wm = wv >> 2, wn = wv & 3;   // wave grid 2 (code) x 4 (x-row)
  const int l31 = lane & 31, lh = lane >> 5;

  // bijective XCD swizzle: 32 consecutive blocks (same ns -> shared A panel) per XCD
  const int lid = blockIdx.x;            // 0..255
  const int swz = (lid & 7) * 32 + (lid >> 3);
  const int ns = swz >> 6, bx = swz & 63;

  const _Float16* gB = Bpack + (size_t)bx * 131072;        // 8 kc * 16384
  const _Float16* gA0 = Apack + (size_t)(ns * 8) * 131072; // 8 code-tiles

  float b1[2] = {-3.0e38f, -3.0e38f};
  float b2[2] = {-3.0e38f, -3.0e38f};
  int idx1[2] = {0, 0};

  // prologue: stage (ct=0, kc=0) into buf0
  {
#pragma unroll
    for (int q = 0; q < 4; ++q) {
      const int sec = wv * 4 + q;
      GLL16(gA0 + sec * 512 + lane * 8, ldsA + sec * 512);
      GLL16(gB + sec * 512 + lane * 8, ldsB + sec * 512);
    }
  }
  WAITV0;
  __builtin_amdgcn_s_barrier();

  for (int ct = 0; ct < 8; ++ct) {
    floatx16 acc[4][2] = {};
    half8 bh[2][2], bl[2][2];

    for (int kc = 0; kc < 8; ++kc) {
      const int bo = (kc & 1) * 16384;
      const int nbo = bo ^ 16384;
      // prefetch source: next kc, or next code-tile's kc=0 (parity: buf0 after kc=7)
      const bool pf = !(ct == 7 && kc == 7);
      const _Float16* gaN;
      const _Float16* gbN;
      if (kc < 7) {
        gaN = gA0 + (size_t)(ct * 8 + kc + 1) * 16384;
        gbN = gB + (size_t)(kc + 1) * 16384;
      } else {
        gaN = gA0 + (size_t)((ct + 1) * 8) * 16384;
        gbN = gB;
      }

#pragma unroll
      for (int p = 0; p < 4; ++p) {
        SCB;
        // A fragments for i = p
        const int abase = bo + (wm * 4 + p) * 2048 + lh * 256 + l31 * 8;
        const half8 ah0 = *reinterpret_cast<const half8*>(ldsA + abase);
        const half8 ah1 = *reinterpret_cast<const half8*>(ldsA + abase + 512);
        const half8 al0 = *reinterpret_cast<const half8*>(ldsA + abase + 1024);
        const half8 al1 = *reinterpret_cast<const half8*>(ldsA + abase + 1536);
        if (p == 0) {
#pragma unroll
          for (int j = 0; j < 2; ++j) {
            const int bbase = bo + (wn * 2 + j) * 2048 + lh * 256 + l31 * 8;
            bh[j][0] = *reinterpret_cast<const half8*>(ldsB + bbase);
            bh[j][1] = *reinterpret_cast<const half8*>(ldsB + bbase + 512);
            bl[j][0] = *reinterpret_cast<const half8*>(ldsB + bbase + 1024);
            bl[j][1] = *reinterpret_cast<const half8*>(ldsB + bbase + 1536);
          }
        }
        if (pf && p < 2) {
#pragma unroll
          for (int q = 0; q < 2; ++q) {
            const int sec = wv * 4 + p * 2 + q;
            GLL16(gaN + sec * 512 + lane * 8, ldsA + nbo + sec * 512);
            GLL16(gbN + sec * 512 + lane * 8, ldsB + nbo + sec * 512);
          }
        }
        SCB;
        __builtin_amdgcn_s_barrier();
        LGKM0;
        __builtin_amdgcn_s_setprio(1);
#pragma unroll
        for (int j = 0; j < 2; ++j) {
          acc[p][j] = MFMA16(ah0, bh[j][0], acc[p][j]);
          acc[p][j] = MFMA16(ah1, bh[j][1], acc[p][j]);
          acc[p][j] = MFMA16(ah0, bl[j][0], acc[p][j]);
          acc[p][j] = MFMA16(ah1, bl[j][1], acc[p][j]);
          acc[p][j] = MFMA16(al0, bh[j][0], acc[p][j]);
          acc[p][j] = MFMA16(al1, bh[j][1], acc[p][j]);
        }
        __builtin_amdgcn_s_setprio(0);
        if (p == 3) { WAITV0; }   // counted drain: prefetched loads had 3 phases in flight
        SCB;
        __builtin_amdgcn_s_barrier();
      }
    }

    // epilogue: scores + running per-lane top-2 (en2 straight from L2)
    const int ctbase = (ns * 8 + ct) * 256;
#pragma unroll
    for (int i = 0; i < 4; ++i) {
      const float* ep = en2 + ctbase + wm * 128 + i * 32 + 4 * lh;
      const float4 e0 = *reinterpret_cast<const float4*>(ep);
      const float4 e1 = *reinterpret_cast<const float4*>(ep + 8);
      const float4 e2 = *reinterpret_cast<const float4*>(ep + 16);
      const float4 e3 = *reinterpret_cast<const float4*>(ep + 24);
      const float ev[16] = {e0.x, e0.y, e0.z, e0.w, e1.x, e1.y, e1.z, e1.w,
                            e2.x, e2.y, e2.z, e2.w, e3.x, e3.y, e3.z, e3.w};
#pragma unroll
      for (int reg = 0; reg < 16; ++reg) {
        const int code = ctbase + wm * 128 + i * 32 + (reg & 3) + 8 * (reg >> 2) + 4 * lh;
#pragma unroll
        for (int j = 0; j < 2; ++j) {
          const float v = acc[i][j][reg] - ev[reg];
          if (v > b1[j] || (v == b1[j] && code < idx1[j])) {
            b2[j] = b1[j]; b1[j] = v; idx1[j] = code;
          } else if (v > b2[j]) {
            b2[j] = v;
          }
        }
      }
    }
  }

  // merge lane <-> lane^32 (same x-row, disjoint code subsets)
#pragma unroll
  for (int j = 0; j < 2; ++j) {
    const float o1 = __shfl_xor(b1[j], 32, 64);
    const int oi = __shfl_xor(idx1[j], 32, 64);
    const float o2 = __shfl_xor(b2[j], 32, 64);
    const bool win = (b1[j] > o1) || (b1[j] == o1 && idx1[j] < oi);
    const float lose1 = win ? o1 : b1[j];
    b1[j] = win ? b1[j] : o1;
    idx1[j] = win ? idx1[j] : oi;
    b2[j] = fmaxf(fmaxf(b2[j], o2), lose1);
  }

  // cross-wave (wm 0 vs 1) merge via LDS scratch (reuse ldsA)
  float* scr = reinterpret_cast<float*>(ldsA);   // [2][256][3]
  __syncthreads();
  if (lane < 32) {
#pragma unroll
    for (int j = 0; j < 2; ++j) {
      const int row = wn * 64 + j * 32 + l31;
      scr[(wm * 256 + row) * 3 + 0] = b1[j];
      scr[(wm * 256 + row) * 3 + 1] = __int_as_float(idx1[j]);
      scr[(wm * 256 + row) * 3 + 2] = b2[j];
    }
  }
  __syncthreads();
  if (tid < 256) {
    float v1 = scr[tid * 3 + 0];
    int ii = __float_as_int(scr[tid * 3 + 1]);
    float v2 = scr[tid * 3 + 2];
    const float o1 = scr[(256 + tid) * 3 + 0];
    const int oi = __float_as_int(scr[(256 + tid) * 3 + 1]);
    const float o2 = scr[(256 + tid) * 3 + 2];
    const bool win = (v1 > o1) || (v1 == o1 && ii < oi);
    const float lose1 = win ? o1 : v1;
    const float nb1 = win ? v1 : o1;
    const int ni = win ? ii : oi;
    const float nb2 = fmaxf(fmaxf(v2, o2), lose1);
    const int row = bx * 256 + tid;
    candV[(size_t)row * NSPLIT + ns] = nb1;
    candI[(size_t)row * NSPLIT + ns] = ni;
    cand2[(size_t)row * NSPLIT + ns] = nb2;
  }
}

// ---- merge splits -> index, margin; flag risky rows ----
__global__ void vq_reduce(const float* __restrict__ candV, const int* __restrict__ candI,
                          const float* __restrict__ cand2, int* __restrict__ ind,
                          int* __restrict__ cnt, int* __restrict__ risky,
                          unsigned long long* __restrict__ key) {
  const int row = blockIdx.x * blockDim.x + threadIdx.x;
  if (row >= M_ROWS) return;
  float b1 = candV[(size_t)row * NSPLIT];
  int i1 = candI[(size_t)row * NSPLIT];
  float b2 = cand2[(size_t)row * NSPLIT];
#pragma unroll
  for (int s = 1; s < NSPLIT; ++s) {
    const float v = candV[(size_t)row * NSPLIT + s];
    const int ii = candI[(size_t)row * NSPLIT + s];
    const float v2 = cand2[(size_t)row * NSPLIT + s];
    if (v > b1 || (v == b1 && ii < i1)) {
      b2 = fmaxf(b1, v2); b1 = v; i1 = ii;
    } else {
      b2 = fmaxf(b2, v);
    }
  }
  ind[row] = i1;
  if (b1 - b2 < TAU) {
    const int p = atomicAdd(cnt, 1);
    if (p < CAP) { risky[p] = row; key[row] = 0ull; }
  }
}

// ---- exact fp32 rescore of risky rows, striped over RSTRIDE block-columns ----
__global__ __launch_bounds__(256)
void vq_refine(const float* __restrict__ x, const float* __restrict__ cb,
               const float* __restrict__ en2, const int* __restrict__ cnt,
               const int* __restrict__ risky, unsigned long long* __restrict__ key) {
  __shared__ float cbs[16][256];
  __shared__ float xs[256];
  const int n0 = *cnt;
  const int n = n0 < CAP ? n0 : CAP;
  const int stripe = blockIdx.x;
  if (stripe >= n) return;
  const int tid = threadIdx.x;
  const int cBase = blockIdx.y * 16;
#pragma unroll
  for (int q = 0; q < 16; ++q) cbs[q][tid] = cb[(size_t)(cBase + q) * K_DIM + tid];
  const int sub = tid & 15;
  const int cl = tid >> 4;
  for (int t = stripe; t < n; t += RSTRIDE) {
    const int row = risky[t];
    __syncthreads();
    xs[tid] = x[(size_t)row * K_DIM + tid];
    __syncthreads();
    float s = 0.f;
#pragma unroll
    for (int k = 0; k < 16; ++k) s = fmaf(xs[sub * 16 + k], cbs[cl][sub * 16 + k], s);
    s += __shfl_xor(s, 1, 64); s += __shfl_xor(s, 2, 64);
    s += __shfl_xor(s, 4, 64); s += __shfl_xor(s, 8, 64);
    if (sub == 0) {
      const int code = cBase + cl;
      const float sc = s - en2[code];
      unsigned u = __float_as_uint(sc);
      u ^= (u >> 31) ? 0xFFFFFFFFu : 0x80000000u;
      const unsigned long long k64 =
          ((unsigned long long)u << 32) | (unsigned)(N_CODES - 1 - code);
      atomicMax(key + row, k64);
    }
  }
}

__global__ void vq_fix(const int* __restrict__ cnt, const int* __restrict__ risky,
                       const unsigned long long* __restrict__ key, int* __restrict__ ind) {
  const int i = blockIdx.x * blockDim.x + threadIdx.x;
  const int n = *cnt < CAP ? *cnt : CAP;
  if (i < n) {
    const int r = risky[i];
    ind[r] = N_CODES - 1 - (int)(unsigned)(key[r] & 0xFFFFFFFFull);
  }
}

// ---- gather z_q, write z_q_st + indices, partial loss sums ----
__global__ void vq_gather(const float* __restrict__ x, const float* __restrict__ cb,
                          const int* __restrict__ ind, float* __restrict__ zq,
                          float* __restrict__ idxf, float* __restrict__ partial) {
  __shared__ float red[256];
  const int g = blockIdx.x * 256 + threadIdx.x;
  const int row = g >> 6;
  const int c4 = g & 63;
  const int idx = ind[row];
  if (c4 == 0) idxf[row] = (float)idx;
  const float4 z = *reinterpret_cast<const float4*>(cb + (size_t)idx * K_DIM + c4 * 4);
  const float4 xv = *reinterpret_cast<const float4*>(x + (size_t)g * 4);
  *reinterpret_cast<float4*>(zq + (size_t)g * 4) = z;
  const float dx = z.x - xv.x, dy = z.y - xv.y, dz = z.z - xv.z, dw = z.w - xv.w;
  red[threadIdx.x] = dx * dx + dy * dy + dz * dz + dw * dw;
  __syncthreads();
  for (int o = 128; o > 0; o >>= 1) {
    if (threadIdx.x < o) red[threadIdx.x] += red[threadIdx.x + o];
    __syncthreads();
  }
  if (threadIdx.x == 0) partial[blockIdx.x] = red[0];
}

__global__ void vq_loss(const float* __restrict__ partial, float* __restrict__ out) {
  __shared__ float red[256];
  float s = 0.f;
  for (int i = threadIdx.x; i < 4096; i += 256) s += partial[i];
  red[threadIdx.x] = s;
  __syncthreads();
  for (int o = 128; o > 0; o >>= 1) {
    if (threadIdx.x < o) red[threadIdx.x] += red[threadIdx.x + o];
    __syncthreads();
  }
  if (threadIdx.x == 0) out[0] = 1.25f * red[0] / 4194304.0f;
}

extern "C" void kernel_launch(void* const* d_in, const int* in_sizes, int n_in,
                              void* d_out, int out_size, void* d_ws, size_t ws_size,
                              hipStream_t stream) {
  const float* x = (const float*)d_in[0];
  const float* cb = (const float*)d_in[1];
  float* out = (float*)d_out;
  float* zq = out;
  float* loss = out + 4194304;
  float* idxf = out + 4194305;

  char* w = (char*)d_ws;
  _Float16* Apack = (_Float16*)w;                      w += (size_t)N_CODES * K_DIM * 2 * 2;
  _Float16* Bpack = (_Float16*)w;                      w += (size_t)M_ROWS * K_DIM * 2 * 2;
  unsigned long long* key = (unsigned long long*)w;    w += (size_t)M_ROWS * 8;
  float* en2 = (float*)w;                              w += (size_t)N_CODES * 4;
  float* candV = (float*)w;                            w += (size_t)M_ROWS * NSPLIT * 4;
  float* cand2 = (float*)w;                            w += (size_t)M_ROWS * NSPLIT * 4;
  int* candI = (int*)w;                                w += (size_t)M_ROWS * NSPLIT * 4;
  int* ind = (int*)w;                                  w += (size_t)M_ROWS * 4;
  int* risky = (int*)w;                                w += (size_t)CAP * 4;
  int* cnt = (int*)w;                                  w += 64;
  float* part = (float*)w;                             w += 4096 * 4;

  pack_k<<<(N_CODES * 32) / 256, 256, 0, stream>>>(cb, Apack);
  pack_k<<<(M_ROWS * 32) / 256, 256, 0, stream>>>(x, Bpack);
  enorm_k<<<N_CODES / 4, 256, 0, stream>>>(cb, en2, cnt);
  vq_dist<<<256, 512, 0, stream>>>(Apack, Bpack, en2, candV, candI, cand2);
  vq_reduce<<<M_ROWS / 256, 256, 0, stream>>>(candV, candI, cand2, ind, cnt, risky, key);
  vq_refine<<<dim3(RSTRIDE, N_CODES / 16), 256, 0, stream>>>(x, cb, en2, cnt, risky, key);
  vq_fix<<<CAP / 256, 256, 0, stream>>>(cnt, risky, key, ind);
  vq_gather<<<4194304 / (256 * 4), 256, 0, stream>>>(x, cb, ind, zq, idxf, part);
  vq_loss<<<1, 256, 0, stream>>>(part, loss);
}